// Round 4
// baseline (314.480 us; speedup 1.0000x reference)
//
#include <hip/hip_runtime.h>
#include <cstdint>
#include <cstddef>

constexpr int CDIM   = 256;   // channels
constexpr int CR     = 64;    // reduced channels
constexpr int NROW   = 4096;  // tokens per batch
constexpr int NBATCH = 8;
constexpr int GRID   = 1024;            // 4 blocks/CU on 256 CUs
constexpr int BPB    = GRID / NBATCH;   // 128 blocks per batch
constexpr int RPB    = NROW / BPB;      // 32 rows per block
constexpr int RPW    = RPB / 4;         // 8 rows per wave
constexpr int NLEAF  = 64;
constexpr int BPL    = GRID / NLEAF;    // 16 blocks per leaf

// ---- workspace layout (bytes) ----
constexpr size_t OFF_SFIN  = (size_t)GRID * CDIM * sizeof(float);          // S_part: 1 MB
constexpr size_t OFF_BESTS = OFF_SFIN + (size_t)NBATCH * CDIM * sizeof(float); // S_fin: 8 KB
constexpr size_t OFF_BAR   = OFF_BESTS + (size_t)GRID * sizeof(unsigned long long); // bests: 8 KB
// bar words: leaf1[64*16]=0..1023, root1@1024, root2@1040, leaf3@1056..2079, root3@2080
constexpr int BAR_WORDS = 2112;

__global__ __launch_bounds__(256) void k_zero(unsigned* __restrict__ bar) {
    const int t = threadIdx.x;
    for (int i = t; i < BAR_WORDS; i += 256) bar[i] = 0u;
}

__device__ __forceinline__ unsigned ld_acq(unsigned* p) {
    return __hip_atomic_load(p, __ATOMIC_ACQUIRE, __HIP_MEMORY_SCOPE_AGENT);
}
// t==0 only, call after __syncthreads(); makes block's prior global stores visible
__device__ __forceinline__ void arrive(unsigned* leafbase, unsigned* root, int blk) {
    __threadfence();
    unsigned* leaf = leafbase + (blk / BPL) * 16;   // 64B-separated counters
    if (atomicAdd(leaf, 1u) == BPL - 1) atomicAdd(root, 1u);
}
__device__ __forceinline__ void wait_eq(unsigned* root, unsigned target) {
    while (ld_acq(root) < target) __builtin_amdgcn_s_sleep(1);
    __threadfence();
}

__device__ __forceinline__ unsigned long long pack_key(float best, int n) {
    unsigned key = __float_as_uint(best);
    key = (key & 0x80000000u) ? ~key : (key | 0x80000000u);   // order-preserving
    return ((unsigned long long)key << 32) | (unsigned)n;
}

// ======================= primary: single cooperative kernel =======================
__global__ __launch_bounds__(256, 4) void k_fused(
    const float* __restrict__ x,   const float* __restrict__ lnw,
    const float* __restrict__ lnb, const float* __restrict__ pw,
    const float* __restrict__ pb,  float* __restrict__ S_part,
    float* __restrict__ S_fin,     unsigned long long* __restrict__ bests,
    unsigned* __restrict__ bar,    float* __restrict__ out)
{
    const int blk  = blockIdx.x;
    const int t    = threadIdx.x;
    const int wave = t >> 6;
    const int lane = t & 63;

    __shared__ float comb[4][CDIM];           // 4 KB
    __shared__ unsigned long long wbest[4];
    __shared__ float sred[8];

    unsigned* leaf1 = bar;
    unsigned* root1 = bar + 1024;
    unsigned* root2 = bar + 1040;
    unsigned* leaf3 = bar + 1056;
    unsigned* root3 = bar + 2080;

    const int b     = blk / BPB;
    const int chunk = blk % BPB;
    const float* xb = x + (size_t)b * NROW * CDIM;
    const int nbase = chunk * RPB + wave * RPW;

    // ---- phase 1: u rows -> registers; per-block partial S ----
    float4 ur[RPW];
    float a0 = 0.f, a1 = 0.f, a2 = 0.f, a3 = 0.f;
#pragma unroll
    for (int r = 0; r < RPW; ++r) {
        const float4 v = *reinterpret_cast<const float4*>(
            xb + (size_t)(nbase + r) * CDIM + lane * 4);
        float sa = v.x + v.y + v.z + v.w;
        float sb = v.x * v.x + v.y * v.y + v.z * v.z + v.w * v.w;
#pragma unroll
        for (int off = 1; off < 64; off <<= 1) {
            sa += __shfl_xor(sa, off, 64);
            sb += __shfl_xor(sb, off, 64);
        }
        const float mu  = sa * (1.0f / CDIM);
        const float inv = rsqrtf(sb - sa * mu);     // eps & rsqrt scale cancel in u
        ur[r].x = (v.x - mu) * inv;  ur[r].y = (v.y - mu) * inv;
        ur[r].z = (v.z - mu) * inv;  ur[r].w = (v.w - mu) * inv;
        a0 += ur[r].x; a1 += ur[r].y; a2 += ur[r].z; a3 += ur[r].w;
    }
    *reinterpret_cast<float4*>(&comb[wave][lane * 4]) = make_float4(a0, a1, a2, a3);
    __syncthreads();
    S_part[(size_t)blk * CDIM + t] =
        (comb[0][t] + comb[1][t]) + (comb[2][t] + comb[3][t]);
    __syncthreads();
    if (t == 0) arrive(leaf1, root1, blk);

    // ---- reducers (blocks 0..7): S_fin[b] = sum of batch partials ----
    if (blk < NBATCH) {
        if (t == 0) wait_eq(root1, NLEAF);
        __syncthreads();
        const float* Sp = S_part + (size_t)blk * BPB * CDIM;
        float s0 = 0.f, s1 = 0.f, s2 = 0.f, s3 = 0.f;
        for (int p = 0; p < BPB; p += 4) {
            s0 += Sp[(size_t)(p + 0) * CDIM + t];
            s1 += Sp[(size_t)(p + 1) * CDIM + t];
            s2 += Sp[(size_t)(p + 2) * CDIM + t];
            s3 += Sp[(size_t)(p + 3) * CDIM + t];
        }
        S_fin[blk * CDIM + t] = (s0 + s1) + (s2 + s3);
        __syncthreads();
        if (t == 0) { __threadfence(); atomicAdd(root2, 1u); }
    }
    if (t == 0) wait_eq(root2, NBATCH);
    __syncthreads();

    // ---- phase 2: density = u . S from registers; per-block best ----
    const float4 Sv = *reinterpret_cast<const float4*>(S_fin + b * CDIM + lane * 4);
    float best  = -1e30f;
    int   bestn = 0;
#pragma unroll
    for (int r = 0; r < RPW; ++r) {
        float sc = ur[r].x * Sv.x + ur[r].y * Sv.y + ur[r].z * Sv.z + ur[r].w * Sv.w;
#pragma unroll
        for (int off = 1; off < 64; off <<= 1) sc += __shfl_xor(sc, off, 64);
        if (sc > best) { best = sc; bestn = nbase + r; }
    }
    if (lane == 0) wbest[wave] = pack_key(best, bestn);
    __syncthreads();
    if (t == 0) {
        unsigned long long m = wbest[0];
#pragma unroll
        for (int w = 1; w < 4; ++w) m = m > wbest[w] ? m : wbest[w];
        bests[blk] = m;
        arrive(leaf3, root3, blk);   // fences bests store
    }
    if (blk >= NBATCH) return;

    // ---- phase 3 (blocks 0..7): argmax over bests; LN; proj; relu ----
    if (t == 0) wait_eq(root3, NLEAF);
    __syncthreads();

    unsigned long long v64 = (t < BPB) ? bests[(size_t)blk * BPB + t] : 0ULL;
#pragma unroll
    for (int off = 1; off < 64; off <<= 1) {
        const unsigned long long o = __shfl_xor(v64, off, 64);
        v64 = o > v64 ? o : v64;
    }
    if (lane == 0) wbest[wave] = v64;
    __syncthreads();
    unsigned long long m = wbest[0];
#pragma unroll
    for (int w = 1; w < 4; ++w) m = m > wbest[w] ? m : wbest[w];
    const int n = (int)(m & 0xFFFFFFFFULL);

    const float* row = x + ((size_t)blk * NROW + n) * CDIM;
    const float v = row[t];

    float s = v;
#pragma unroll
    for (int off = 1; off < 64; off <<= 1) s += __shfl_xor(s, off, 64);
    if (lane == 0) sred[wave] = s;
    __syncthreads();
    const float mu = (sred[0] + sred[1] + sred[2] + sred[3]) * (1.0f / CDIM);

    const float d = v - mu;
    float s2 = d * d;
#pragma unroll
    for (int off = 1; off < 64; off <<= 1) s2 += __shfl_xor(s2, off, 64);
    if (lane == 0) sred[4 + wave] = s2;
    __syncthreads();
    const float var = (sred[4] + sred[5] + sred[6] + sred[7]) * (1.0f / CDIM);
    const float rs  = rsqrtf(var + 1e-5f);

    comb[0][t] = d * rs * lnw[t] + lnb[t];   // y
    __syncthreads();

    const int dcol = t >> 2;
    const int part = t & 3;
    const float* wrow = pw + dcol * CDIM + part * 64;
    const float* yp   = &comb[0][part * 64];
    float p = 0.f;
#pragma unroll
    for (int c = 0; c < 64; ++c) p += yp[c] * wrow[c];
    p += __shfl_xor(p, 1, 64);
    p += __shfl_xor(p, 2, 64);
    if (part == 0) out[blk * CR + dcol] = fmaxf(p + pb[dcol], 0.0f);
}

// ======================= fallback: 4 normal kernels =======================
__global__ __launch_bounds__(256) void kA(const float* __restrict__ x,
                                          float* __restrict__ S_part) {
    const int blk = blockIdx.x, t = threadIdx.x, wave = t >> 6, lane = t & 63;
    __shared__ float comb[4][CDIM];
    const int b = blk / BPB, chunk = blk % BPB;
    const float* xb = x + (size_t)b * NROW * CDIM;
    const int nbase = chunk * RPB + wave * RPW;
    float a0 = 0.f, a1 = 0.f, a2 = 0.f, a3 = 0.f;
    for (int r = 0; r < RPW; ++r) {
        const float4 v = *reinterpret_cast<const float4*>(
            xb + (size_t)(nbase + r) * CDIM + lane * 4);
        float sa = v.x + v.y + v.z + v.w;
        float sb = v.x * v.x + v.y * v.y + v.z * v.z + v.w * v.w;
#pragma unroll
        for (int off = 1; off < 64; off <<= 1) {
            sa += __shfl_xor(sa, off, 64); sb += __shfl_xor(sb, off, 64);
        }
        const float mu = sa * (1.0f / CDIM);
        const float inv = rsqrtf(sb - sa * mu);
        a0 += (v.x - mu) * inv; a1 += (v.y - mu) * inv;
        a2 += (v.z - mu) * inv; a3 += (v.w - mu) * inv;
    }
    *reinterpret_cast<float4*>(&comb[wave][lane * 4]) = make_float4(a0, a1, a2, a3);
    __syncthreads();
    S_part[(size_t)blk * CDIM + t] =
        (comb[0][t] + comb[1][t]) + (comb[2][t] + comb[3][t]);
}
__global__ __launch_bounds__(256) void kB(const float* __restrict__ S_part,
                                          float* __restrict__ S_fin) {
    const int bb = blockIdx.x, t = threadIdx.x;
    const float* Sp = S_part + (size_t)bb * BPB * CDIM;
    float s = 0.f;
    for (int p = 0; p < BPB; ++p) s += Sp[(size_t)p * CDIM + t];
    S_fin[bb * CDIM + t] = s;
}
__global__ __launch_bounds__(256) void kC(const float* __restrict__ x,
                                          const float* __restrict__ S_fin,
                                          unsigned long long* __restrict__ bests) {
    const int blk = blockIdx.x, t = threadIdx.x, wave = t >> 6, lane = t & 63;
    __shared__ unsigned long long wbest[4];
    const int b = blk / BPB, chunk = blk % BPB;
    const float* xb = x + (size_t)b * NROW * CDIM;
    const int nbase = chunk * RPB + wave * RPW;
    const float4 Sv = *reinterpret_cast<const float4*>(S_fin + b * CDIM + lane * 4);
    float sumS = Sv.x + Sv.y + Sv.z + Sv.w;
#pragma unroll
    for (int off = 1; off < 64; off <<= 1) sumS += __shfl_xor(sumS, off, 64);
    float best = -1e30f; int bestn = 0;
    for (int r = 0; r < RPW; ++r) {
        const float4 v = *reinterpret_cast<const float4*>(
            xb + (size_t)(nbase + r) * CDIM + lane * 4);
        float sa = v.x + v.y + v.z + v.w;
        float sb = v.x * v.x + v.y * v.y + v.z * v.z + v.w * v.w;
        float sc = v.x * Sv.x + v.y * Sv.y + v.z * Sv.z + v.w * Sv.w;
#pragma unroll
        for (int off = 1; off < 64; off <<= 1) {
            sa += __shfl_xor(sa, off, 64); sb += __shfl_xor(sb, off, 64);
            sc += __shfl_xor(sc, off, 64);
        }
        const float mu = sa * (1.0f / CDIM);
        const float dens = (sc - mu * sumS) * rsqrtf(sb - sa * mu);
        if (dens > best) { best = dens; bestn = nbase + r; }
    }
    if (lane == 0) wbest[wave] = pack_key(best, bestn);
    __syncthreads();
    if (t == 0) {
        unsigned long long m = wbest[0];
#pragma unroll
        for (int w = 1; w < 4; ++w) m = m > wbest[w] ? m : wbest[w];
        bests[blk] = m;
    }
}
__global__ __launch_bounds__(256) void kD(const float* __restrict__ x,
                                          const float* __restrict__ lnw,
                                          const float* __restrict__ lnb,
                                          const float* __restrict__ pw,
                                          const float* __restrict__ pb,
                                          const unsigned long long* __restrict__ bests,
                                          float* __restrict__ out) {
    const int bb = blockIdx.x, t = threadIdx.x, wave = t >> 6, lane = t & 63;
    __shared__ unsigned long long wbest[4];
    __shared__ float sred[8];
    __shared__ float y[CDIM];
    unsigned long long v64 = (t < BPB) ? bests[(size_t)bb * BPB + t] : 0ULL;
#pragma unroll
    for (int off = 1; off < 64; off <<= 1) {
        const unsigned long long o = __shfl_xor(v64, off, 64);
        v64 = o > v64 ? o : v64;
    }
    if (lane == 0) wbest[wave] = v64;
    __syncthreads();
    unsigned long long m = wbest[0];
#pragma unroll
    for (int w = 1; w < 4; ++w) m = m > wbest[w] ? m : wbest[w];
    const int n = (int)(m & 0xFFFFFFFFULL);
    const float* row = x + ((size_t)bb * NROW + n) * CDIM;
    const float v = row[t];
    float s = v;
#pragma unroll
    for (int off = 1; off < 64; off <<= 1) s += __shfl_xor(s, off, 64);
    if (lane == 0) sred[wave] = s;
    __syncthreads();
    const float mu = (sred[0] + sred[1] + sred[2] + sred[3]) * (1.0f / CDIM);
    const float d = v - mu;
    float s2 = d * d;
#pragma unroll
    for (int off = 1; off < 64; off <<= 1) s2 += __shfl_xor(s2, off, 64);
    if (lane == 0) sred[4 + wave] = s2;
    __syncthreads();
    const float var = (sred[4] + sred[5] + sred[6] + sred[7]) * (1.0f / CDIM);
    const float rs = rsqrtf(var + 1e-5f);
    y[t] = d * rs * lnw[t] + lnb[t];
    __syncthreads();
    const int dcol = t >> 2, part = t & 3;
    const float* wrow = pw + dcol * CDIM + part * 64;
    const float* yp = y + part * 64;
    float p = 0.f;
#pragma unroll
    for (int c = 0; c < 64; ++c) p += yp[c] * wrow[c];
    p += __shfl_xor(p, 1, 64);
    p += __shfl_xor(p, 2, 64);
    if (part == 0) out[bb * CR + dcol] = fmaxf(p + pb[dcol], 0.0f);
}

// ------------------------------------------------------------------ launch ----
extern "C" void kernel_launch(void* const* d_in, const int* in_sizes, int n_in,
                              void* d_out, int out_size, void* d_ws, size_t ws_size,
                              hipStream_t stream) {
    const float* x   = (const float*)d_in[0];
    const float* lnw = (const float*)d_in[1];
    const float* lnb = (const float*)d_in[2];
    const float* pw  = (const float*)d_in[3];
    const float* pb  = (const float*)d_in[4];
    float* out = (float*)d_out;

    float* S_part = (float*)d_ws;
    float* S_fin  = (float*)((char*)d_ws + OFF_SFIN);
    unsigned long long* bests = (unsigned long long*)((char*)d_ws + OFF_BESTS);
    unsigned* bar = (unsigned*)((char*)d_ws + OFF_BAR);

    k_zero<<<1, 256, 0, stream>>>(bar);

    void* args[] = {
        (void*)&x, (void*)&lnw, (void*)&lnb, (void*)&pw, (void*)&pb,
        (void*)&S_part, (void*)&S_fin, (void*)&bests, (void*)&bar, (void*)&out
    };
    const hipError_t e = hipLaunchCooperativeKernel(
        (const void*)k_fused, dim3(GRID), dim3(256), args, 0, stream);
    if (e != hipSuccess) {   // fallback: normal-launch pipeline
        kA<<<GRID,   256, 0, stream>>>(x, S_part);
        kB<<<NBATCH, 256, 0, stream>>>(S_part, S_fin);
        kC<<<GRID,   256, 0, stream>>>(x, S_fin, bests);
        kD<<<NBATCH, 256, 0, stream>>>(x, lnw, lnb, pw, pb, bests, out);
    }
}

// Round 5
// 61.563 us; speedup vs baseline: 5.1083x; 5.1083x over previous
//
#include <hip/hip_runtime.h>
#include <cstdint>
#include <cstddef>

constexpr int CDIM   = 256;   // channels
constexpr int CR     = 64;    // reduced channels
constexpr int NROW   = 4096;  // tokens per batch
constexpr int NBATCH = 8;
constexpr int GRID   = 1024;
constexpr int BPB    = GRID / NBATCH;   // 128 blocks per batch
constexpr int RPB    = NROW / BPB;      // 32 rows per block
constexpr int RPW    = RPB / 4;         // 8 rows per wave

// ws layout: S_part [GRID*CDIM] f32 (1 MB) | cnt [8] u32 (pad to 64B) | amax [8] u64
constexpr size_t OFF_CNT  = (size_t)GRID * CDIM * sizeof(float);
constexpr size_t OFF_AMAX = OFF_CNT + 64;

__device__ __forceinline__ unsigned long long pack_key(float best, int n) {
    unsigned key = __float_as_uint(best);
    key = (key & 0x80000000u) ? ~key : (key | 0x80000000u);   // order-preserving
    return ((unsigned long long)key << 32) | (unsigned)n;
}

// ---- K1: per-block partial S; block 0 zeroes K2's sync state ----
__global__ __launch_bounds__(256) void k1(const float* __restrict__ x,
                                          float* __restrict__ S_part,
                                          unsigned* __restrict__ cnt,
                                          unsigned long long* __restrict__ amax) {
    const int blk = blockIdx.x, t = threadIdx.x, wave = t >> 6, lane = t & 63;
    if (blk == 0 && t < NBATCH) { cnt[t] = 0u; amax[t] = 0ULL; }

    __shared__ float comb[4][CDIM];
    const int b = blk / BPB, chunk = blk % BPB;
    const float* xb = x + (size_t)b * NROW * CDIM;
    const int nbase = chunk * RPB + wave * RPW;

    float a0 = 0.f, a1 = 0.f, a2 = 0.f, a3 = 0.f;
#pragma unroll
    for (int r = 0; r < RPW; ++r) {
        const float4 v = *reinterpret_cast<const float4*>(
            xb + (size_t)(nbase + r) * CDIM + lane * 4);
        float sa = v.x + v.y + v.z + v.w;
        float sb = v.x * v.x + v.y * v.y + v.z * v.z + v.w * v.w;
#pragma unroll
        for (int off = 1; off < 64; off <<= 1) {
            sa += __shfl_xor(sa, off, 64);
            sb += __shfl_xor(sb, off, 64);
        }
        const float mu  = sa * (1.0f / CDIM);
        const float inv = rsqrtf(sb - sa * mu);   // ln-eps & rsqrt scale cancel in u
        a0 += (v.x - mu) * inv;
        a1 += (v.y - mu) * inv;
        a2 += (v.z - mu) * inv;
        a3 += (v.w - mu) * inv;
    }
    *reinterpret_cast<float4*>(&comb[wave][lane * 4]) = make_float4(a0, a1, a2, a3);
    __syncthreads();
    S_part[(size_t)blk * CDIM + t] =
        (comb[0][t] + comb[1][t]) + (comb[2][t] + comb[3][t]);
}

// ---- K2: reduce partials (redundant per block), density, argmax,
//          last-block-per-batch finalizes LN+proj+ReLU. No spinning. ----
__global__ __launch_bounds__(256) void k2(const float* __restrict__ x,
                                          const float* __restrict__ lnw,
                                          const float* __restrict__ lnb,
                                          const float* __restrict__ pw,
                                          const float* __restrict__ pb,
                                          const float* __restrict__ S_part,
                                          unsigned* __restrict__ cnt,
                                          unsigned long long* __restrict__ amax,
                                          float* __restrict__ out) {
    const int blk = blockIdx.x, t = threadIdx.x, wave = t >> 6, lane = t & 63;
    const int b = blk / BPB, chunk = blk % BPB;

    __shared__ float comb[CDIM];
    __shared__ unsigned long long wbest[4];
    __shared__ int lastflag;
    __shared__ float sred[8];

    // S[b][t] = sum of this batch's 128 partials (parallel, redundant, no wait)
    {
        const float* Sp = S_part + (size_t)b * BPB * CDIM;
        float s0 = 0.f, s1 = 0.f, s2 = 0.f, s3 = 0.f;
        for (int p = 0; p < BPB; p += 4) {
            s0 += Sp[(size_t)(p + 0) * CDIM + t];
            s1 += Sp[(size_t)(p + 1) * CDIM + t];
            s2 += Sp[(size_t)(p + 2) * CDIM + t];
            s3 += Sp[(size_t)(p + 3) * CDIM + t];
        }
        comb[t] = (s0 + s1) + (s2 + s3);
    }
    __syncthreads();
    const float4 Sv = *reinterpret_cast<const float4*>(&comb[lane * 4]);
    float sumS = Sv.x + Sv.y + Sv.z + Sv.w;
#pragma unroll
    for (int off = 1; off < 64; off <<= 1) sumS += __shfl_xor(sumS, off, 64);

    // density for this block's 32 rows (x re-read, L3-hot)
    const float* xb = x + (size_t)b * NROW * CDIM;
    const int nbase = chunk * RPB + wave * RPW;
    float best = -1e30f;
    int   bestn = 0;
#pragma unroll
    for (int r = 0; r < RPW; ++r) {
        const float4 v = *reinterpret_cast<const float4*>(
            xb + (size_t)(nbase + r) * CDIM + lane * 4);
        float sa = v.x + v.y + v.z + v.w;
        float sb = v.x * v.x + v.y * v.y + v.z * v.z + v.w * v.w;
        float sc = v.x * Sv.x + v.y * Sv.y + v.z * Sv.z + v.w * Sv.w;
#pragma unroll
        for (int off = 1; off < 64; off <<= 1) {
            sa += __shfl_xor(sa, off, 64);
            sb += __shfl_xor(sb, off, 64);
            sc += __shfl_xor(sc, off, 64);
        }
        const float mu   = sa * (1.0f / CDIM);
        const float dens = (sc - mu * sumS) * rsqrtf(sb - sa * mu);
        if (dens > best) { best = dens; bestn = nbase + r; }
    }
    if (lane == 0) wbest[wave] = pack_key(best, bestn);
    __syncthreads();
    if (t == 0) {
        unsigned long long m = wbest[0];
#pragma unroll
        for (int w = 1; w < 4; ++w) m = m > wbest[w] ? m : wbest[w];
        atomicMax(&amax[b], m);
        __threadfence();                           // max visible before count
        const unsigned old = atomicAdd(&cnt[b], 1u);
        lastflag = (old == BPB - 1);
    }
    __syncthreads();
    if (!lastflag) return;

    // ---- finalizer (one block per batch): LN(argmax row) -> proj -> relu ----
    __threadfence();
    const unsigned long long m = atomicMax(&amax[b], 0ULL);   // coherent read
    const int n = (int)(m & 0xFFFFFFFFULL);

    const float* row = x + ((size_t)b * NROW + n) * CDIM;
    const float v = row[t];

    float s = v;
#pragma unroll
    for (int off = 1; off < 64; off <<= 1) s += __shfl_xor(s, off, 64);
    if (lane == 0) sred[wave] = s;
    __syncthreads();
    const float mu = (sred[0] + sred[1] + sred[2] + sred[3]) * (1.0f / CDIM);

    const float d = v - mu;
    float s2 = d * d;
#pragma unroll
    for (int off = 1; off < 64; off <<= 1) s2 += __shfl_xor(s2, off, 64);
    if (lane == 0) sred[4 + wave] = s2;
    __syncthreads();
    const float var = (sred[4] + sred[5] + sred[6] + sred[7]) * (1.0f / CDIM);
    const float rs  = rsqrtf(var + 1e-5f);

    __syncthreads();                     // comb: S -> y reuse
    comb[t] = d * rs * lnw[t] + lnb[t];
    __syncthreads();

    const int dcol = t >> 2;
    const int part = t & 3;
    const float* wrow = pw + dcol * CDIM + part * 64;
    const float* yp   = &comb[part * 64];
    float p = 0.f;
#pragma unroll
    for (int c = 0; c < 64; ++c) p += yp[c] * wrow[c];
    p += __shfl_xor(p, 1, 64);
    p += __shfl_xor(p, 2, 64);
    if (part == 0) out[b * CR + dcol] = fmaxf(p + pb[dcol], 0.0f);
}

// ------------------------------------------------------------------ launch ----
extern "C" void kernel_launch(void* const* d_in, const int* in_sizes, int n_in,
                              void* d_out, int out_size, void* d_ws, size_t ws_size,
                              hipStream_t stream) {
    const float* x   = (const float*)d_in[0];
    const float* lnw = (const float*)d_in[1];
    const float* lnb = (const float*)d_in[2];
    const float* pw  = (const float*)d_in[3];
    const float* pb  = (const float*)d_in[4];
    float* out = (float*)d_out;

    float* S_part = (float*)d_ws;
    unsigned* cnt = (unsigned*)((char*)d_ws + OFF_CNT);
    unsigned long long* amax = (unsigned long long*)((char*)d_ws + OFF_AMAX);

    k1<<<GRID, 256, 0, stream>>>(x, S_part, cnt, amax);
    k2<<<GRID, 256, 0, stream>>>(x, lnw, lnb, pw, pb, S_part, cnt, amax, out);
}

// Round 6
// 28.911 us; speedup vs baseline: 10.8776x; 2.1294x over previous
//
#include <hip/hip_runtime.h>
#include <cstdint>
#include <cstddef>

constexpr int CDIM   = 256;   // channels
constexpr int CR     = 64;    // reduced channels
constexpr int NROW   = 4096;  // tokens per batch
constexpr int NBATCH = 8;
constexpr int GRID   = 1024;
constexpr int BPB    = GRID / NBATCH;   // 128 blocks per batch
constexpr int RPB    = NROW / BPB;      // 32 rows per block
constexpr int RPW    = RPB / 4;         // 8 rows per wave
constexpr int NMID   = 8;               // mid-partials per batch
constexpr int PPM    = BPB / NMID;      // 16 partials per mid

// ws: S_part [1024*256] f32 (1 MB) | S_mid [64*256] f32 (64 KB) | bests [1024] u64 (8 KB)
constexpr size_t OFF_MID   = (size_t)GRID * CDIM * sizeof(float);
constexpr size_t OFF_BESTS = OFF_MID + (size_t)NBATCH * NMID * CDIM * sizeof(float);

__device__ __forceinline__ unsigned long long pack_key(float best, int n) {
    unsigned key = __float_as_uint(best);
    key = (key & 0x80000000u) ? ~key : (key | 0x80000000u);   // order-preserving
    return ((unsigned long long)key << 32) | (unsigned)n;
}

// ---- k1: per-block partial S (plain stores, no init needed) ----
__global__ __launch_bounds__(256) void k1(const float* __restrict__ x,
                                          float* __restrict__ S_part) {
    const int blk = blockIdx.x, t = threadIdx.x, wave = t >> 6, lane = t & 63;
    __shared__ float comb[4][CDIM];
    const int b = blk / BPB, chunk = blk % BPB;
    const float* xb = x + (size_t)b * NROW * CDIM;
    const int nbase = chunk * RPB + wave * RPW;

    float a0 = 0.f, a1 = 0.f, a2 = 0.f, a3 = 0.f;
#pragma unroll
    for (int r = 0; r < RPW; ++r) {
        const float4 v = *reinterpret_cast<const float4*>(
            xb + (size_t)(nbase + r) * CDIM + lane * 4);
        float sa = v.x + v.y + v.z + v.w;
        float sb = v.x * v.x + v.y * v.y + v.z * v.z + v.w * v.w;
#pragma unroll
        for (int off = 1; off < 64; off <<= 1) {
            sa += __shfl_xor(sa, off, 64);
            sb += __shfl_xor(sb, off, 64);
        }
        const float mu  = sa * (1.0f / CDIM);
        const float inv = rsqrtf(sb - sa * mu);   // ln-eps & rsqrt scale cancel in u
        a0 += (v.x - mu) * inv;
        a1 += (v.y - mu) * inv;
        a2 += (v.z - mu) * inv;
        a3 += (v.w - mu) * inv;
    }
    *reinterpret_cast<float4*>(&comb[wave][lane * 4]) = make_float4(a0, a1, a2, a3);
    __syncthreads();
    S_part[(size_t)blk * CDIM + t] =
        (comb[0][t] + comb[1][t]) + (comb[2][t] + comb[3][t]);
}

// ---- ks: fold 16 partials -> 1 mid-partial (64 blocks) ----
__global__ __launch_bounds__(256) void ks(const float* __restrict__ S_part,
                                          float* __restrict__ S_mid) {
    const int blk = blockIdx.x, t = threadIdx.x;
    const int b = blk / NMID, j = blk % NMID;
    const float* Sp = S_part + ((size_t)b * BPB + (size_t)j * PPM) * CDIM;
    float s0 = 0.f, s1 = 0.f, s2 = 0.f, s3 = 0.f;
#pragma unroll
    for (int p = 0; p < PPM; p += 4) {
        s0 += Sp[(size_t)(p + 0) * CDIM + t];
        s1 += Sp[(size_t)(p + 1) * CDIM + t];
        s2 += Sp[(size_t)(p + 2) * CDIM + t];
        s3 += Sp[(size_t)(p + 3) * CDIM + t];
    }
    S_mid[(size_t)blk * CDIM + t] = (s0 + s1) + (s2 + s3);
}

// ---- k3: S from 8 mids; density for 32 rows; per-block best (plain store) ----
__global__ __launch_bounds__(256) void k3(const float* __restrict__ x,
                                          const float* __restrict__ S_mid,
                                          unsigned long long* __restrict__ bests) {
    const int blk = blockIdx.x, t = threadIdx.x, wave = t >> 6, lane = t & 63;
    const int b = blk / BPB, chunk = blk % BPB;

    __shared__ float comb[CDIM];
    __shared__ unsigned long long wbest[4];

    {
        const float* Sm = S_mid + (size_t)b * NMID * CDIM;
        float s0 = 0.f, s1 = 0.f, s2 = 0.f, s3 = 0.f;
#pragma unroll
        for (int j = 0; j < NMID; j += 4) {
            s0 += Sm[(size_t)(j + 0) * CDIM + t];
            s1 += Sm[(size_t)(j + 1) * CDIM + t];
            s2 += Sm[(size_t)(j + 2) * CDIM + t];
            s3 += Sm[(size_t)(j + 3) * CDIM + t];
        }
        comb[t] = (s0 + s1) + (s2 + s3);
    }
    __syncthreads();
    const float4 Sv = *reinterpret_cast<const float4*>(&comb[lane * 4]);
    float sumS = Sv.x + Sv.y + Sv.z + Sv.w;
#pragma unroll
    for (int off = 1; off < 64; off <<= 1) sumS += __shfl_xor(sumS, off, 64);

    const float* xb = x + (size_t)b * NROW * CDIM;
    const int nbase = chunk * RPB + wave * RPW;
    float best = -1e30f;
    int   bestn = 0;
#pragma unroll
    for (int r = 0; r < RPW; ++r) {
        const float4 v = *reinterpret_cast<const float4*>(
            xb + (size_t)(nbase + r) * CDIM + lane * 4);
        float sa = v.x + v.y + v.z + v.w;
        float sb = v.x * v.x + v.y * v.y + v.z * v.z + v.w * v.w;
        float sc = v.x * Sv.x + v.y * Sv.y + v.z * Sv.z + v.w * Sv.w;
#pragma unroll
        for (int off = 1; off < 64; off <<= 1) {
            sa += __shfl_xor(sa, off, 64);
            sb += __shfl_xor(sb, off, 64);
            sc += __shfl_xor(sc, off, 64);
        }
        const float mu   = sa * (1.0f / CDIM);
        const float dens = (sc - mu * sumS) * rsqrtf(sb - sa * mu);
        if (dens > best) { best = dens; bestn = nbase + r; }
    }
    if (lane == 0) wbest[wave] = pack_key(best, bestn);
    __syncthreads();
    if (t == 0) {
        unsigned long long m = wbest[0];
#pragma unroll
        for (int w = 1; w < 4; ++w) m = m > wbest[w] ? m : wbest[w];
        bests[blk] = m;
    }
}

// ---- k4: argmax over 128 bests; LN(argmax row) -> proj -> relu (8 blocks) ----
__global__ __launch_bounds__(256) void k4(const float* __restrict__ x,
                                          const float* __restrict__ lnw,
                                          const float* __restrict__ lnb,
                                          const float* __restrict__ pw,
                                          const float* __restrict__ pb,
                                          const unsigned long long* __restrict__ bests,
                                          float* __restrict__ out) {
    const int bb = blockIdx.x, t = threadIdx.x, wave = t >> 6, lane = t & 63;
    __shared__ unsigned long long wbest[4];
    __shared__ float sred[8];
    __shared__ float y[CDIM];

    unsigned long long v64 = (t < BPB) ? bests[(size_t)bb * BPB + t] : 0ULL;
#pragma unroll
    for (int off = 1; off < 64; off <<= 1) {
        const unsigned long long o = __shfl_xor(v64, off, 64);
        v64 = o > v64 ? o : v64;
    }
    if (lane == 0) wbest[wave] = v64;
    __syncthreads();
    unsigned long long m = wbest[0];
#pragma unroll
    for (int w = 1; w < 4; ++w) m = m > wbest[w] ? m : wbest[w];
    const int n = (int)(m & 0xFFFFFFFFULL);

    const float* row = x + ((size_t)bb * NROW + n) * CDIM;
    const float v = row[t];

    float s = v;
#pragma unroll
    for (int off = 1; off < 64; off <<= 1) s += __shfl_xor(s, off, 64);
    if (lane == 0) sred[wave] = s;
    __syncthreads();
    const float mu = (sred[0] + sred[1] + sred[2] + sred[3]) * (1.0f / CDIM);

    const float d = v - mu;
    float s2 = d * d;
#pragma unroll
    for (int off = 1; off < 64; off <<= 1) s2 += __shfl_xor(s2, off, 64);
    if (lane == 0) sred[4 + wave] = s2;
    __syncthreads();
    const float var = (sred[4] + sred[5] + sred[6] + sred[7]) * (1.0f / CDIM);
    const float rs  = rsqrtf(var + 1e-5f);

    y[t] = d * rs * lnw[t] + lnb[t];
    __syncthreads();

    const int dcol = t >> 2;
    const int part = t & 3;
    const float* wrow = pw + dcol * CDIM + part * 64;
    const float* yp   = y + part * 64;
    float p = 0.f;
#pragma unroll
    for (int c = 0; c < 64; ++c) p += yp[c] * wrow[c];
    p += __shfl_xor(p, 1, 64);
    p += __shfl_xor(p, 2, 64);
    if (part == 0) out[bb * CR + dcol] = fmaxf(p + pb[dcol], 0.0f);
}

// ------------------------------------------------------------------ launch ----
extern "C" void kernel_launch(void* const* d_in, const int* in_sizes, int n_in,
                              void* d_out, int out_size, void* d_ws, size_t ws_size,
                              hipStream_t stream) {
    const float* x   = (const float*)d_in[0];
    const float* lnw = (const float*)d_in[1];
    const float* lnb = (const float*)d_in[2];
    const float* pw  = (const float*)d_in[3];
    const float* pb  = (const float*)d_in[4];
    float* out = (float*)d_out;

    float* S_part = (float*)d_ws;
    float* S_mid  = (float*)((char*)d_ws + OFF_MID);
    unsigned long long* bests = (unsigned long long*)((char*)d_ws + OFF_BESTS);

    k1<<<GRID,          256, 0, stream>>>(x, S_part);
    ks<<<NBATCH * NMID, 256, 0, stream>>>(S_part, S_mid);
    k3<<<GRID,          256, 0, stream>>>(x, S_mid, bests);
    k4<<<NBATCH,        256, 0, stream>>>(x, lnw, lnb, pw, pb, bests, out);
}

// Round 7
// 28.890 us; speedup vs baseline: 10.8852x; 1.0007x over previous
//
#include <hip/hip_runtime.h>
#include <cstdint>
#include <cstddef>

constexpr int CDIM   = 256;   // channels
constexpr int CR     = 64;    // reduced channels
constexpr int NROW   = 4096;  // tokens per batch
constexpr int NBATCH = 8;
constexpr int GRID   = 1024;
constexpr int BPB    = GRID / NBATCH;   // 128 blocks per batch
constexpr int RPB    = NROW / BPB;      // 32 rows per block
constexpr int RPW    = RPB / 4;         // 8 rows per wave
constexpr int NMID   = 8;               // mid-partials per batch
constexpr int PPM    = BPB / NMID;      // 16 partials per mid

// ws: S_part [1024*256] f32 (1 MB) | S_mid [64*256] f32 (64 KB) | bests [1024] u64 (8 KB)
constexpr size_t OFF_MID   = (size_t)GRID * CDIM * sizeof(float);
constexpr size_t OFF_BESTS = OFF_MID + (size_t)NBATCH * NMID * CDIM * sizeof(float);

__device__ __forceinline__ unsigned long long pack_key(float best, int n) {
    unsigned key = __float_as_uint(best);
    key = (key & 0x80000000u) ? ~key : (key | 0x80000000u);   // order-preserving
    return ((unsigned long long)key << 32) | (unsigned)n;
}

// ---- k1: per-block partial S (plain stores, no init needed) ----
__global__ __launch_bounds__(256) void k1(const float* __restrict__ x,
                                          float* __restrict__ S_part) {
    const int blk = blockIdx.x, t = threadIdx.x, wave = t >> 6, lane = t & 63;
    __shared__ float comb[4][CDIM];
    const int b = blk / BPB, chunk = blk % BPB;
    const float* xb = x + (size_t)b * NROW * CDIM;
    const int nbase = chunk * RPB + wave * RPW;

    float a0 = 0.f, a1 = 0.f, a2 = 0.f, a3 = 0.f;
#pragma unroll
    for (int r = 0; r < RPW; ++r) {
        const float4 v = *reinterpret_cast<const float4*>(
            xb + (size_t)(nbase + r) * CDIM + lane * 4);
        float sa = v.x + v.y + v.z + v.w;
        float sb = v.x * v.x + v.y * v.y + v.z * v.z + v.w * v.w;
#pragma unroll
        for (int off = 1; off < 64; off <<= 1) {
            sa += __shfl_xor(sa, off, 64);
            sb += __shfl_xor(sb, off, 64);
        }
        const float mu  = sa * (1.0f / CDIM);
        const float inv = rsqrtf(sb - sa * mu);   // ln-eps & rsqrt scale cancel in u
        a0 += (v.x - mu) * inv;
        a1 += (v.y - mu) * inv;
        a2 += (v.z - mu) * inv;
        a3 += (v.w - mu) * inv;
    }
    *reinterpret_cast<float4*>(&comb[wave][lane * 4]) = make_float4(a0, a1, a2, a3);
    __syncthreads();
    S_part[(size_t)blk * CDIM + t] =
        (comb[0][t] + comb[1][t]) + (comb[2][t] + comb[3][t]);
}

// ---- ks: fold 16 partials -> 1 mid-partial (64 blocks) ----
__global__ __launch_bounds__(256) void ks(const float* __restrict__ S_part,
                                          float* __restrict__ S_mid) {
    const int blk = blockIdx.x, t = threadIdx.x;
    const int b = blk / NMID, j = blk % NMID;
    const float* Sp = S_part + ((size_t)b * BPB + (size_t)j * PPM) * CDIM;
    float s0 = 0.f, s1 = 0.f, s2 = 0.f, s3 = 0.f;
#pragma unroll
    for (int p = 0; p < PPM; p += 4) {
        s0 += Sp[(size_t)(p + 0) * CDIM + t];
        s1 += Sp[(size_t)(p + 1) * CDIM + t];
        s2 += Sp[(size_t)(p + 2) * CDIM + t];
        s3 += Sp[(size_t)(p + 3) * CDIM + t];
    }
    S_mid[(size_t)blk * CDIM + t] = (s0 + s1) + (s2 + s3);
}

// ---- k3: S from 8 mids; density for 32 rows; per-block best (plain store) ----
__global__ __launch_bounds__(256) void k3(const float* __restrict__ x,
                                          const float* __restrict__ S_mid,
                                          unsigned long long* __restrict__ bests) {
    const int blk = blockIdx.x, t = threadIdx.x, wave = t >> 6, lane = t & 63;
    const int b = blk / BPB, chunk = blk % BPB;

    __shared__ float comb[CDIM];
    __shared__ unsigned long long wbest[4];

    {
        const float* Sm = S_mid + (size_t)b * NMID * CDIM;
        float s0 = 0.f, s1 = 0.f, s2 = 0.f, s3 = 0.f;
#pragma unroll
        for (int j = 0; j < NMID; j += 4) {
            s0 += Sm[(size_t)(j + 0) * CDIM + t];
            s1 += Sm[(size_t)(j + 1) * CDIM + t];
            s2 += Sm[(size_t)(j + 2) * CDIM + t];
            s3 += Sm[(size_t)(j + 3) * CDIM + t];
        }
        comb[t] = (s0 + s1) + (s2 + s3);
    }
    __syncthreads();
    const float4 Sv = *reinterpret_cast<const float4*>(&comb[lane * 4]);
    float sumS = Sv.x + Sv.y + Sv.z + Sv.w;
#pragma unroll
    for (int off = 1; off < 64; off <<= 1) sumS += __shfl_xor(sumS, off, 64);

    const float* xb = x + (size_t)b * NROW * CDIM;
    const int nbase = chunk * RPB + wave * RPW;
    float best = -1e30f;
    int   bestn = 0;
#pragma unroll
    for (int r = 0; r < RPW; ++r) {
        const float4 v = *reinterpret_cast<const float4*>(
            xb + (size_t)(nbase + r) * CDIM + lane * 4);
        float sa = v.x + v.y + v.z + v.w;
        float sb = v.x * v.x + v.y * v.y + v.z * v.z + v.w * v.w;
        float sc = v.x * Sv.x + v.y * Sv.y + v.z * Sv.z + v.w * Sv.w;
#pragma unroll
        for (int off = 1; off < 64; off <<= 1) {
            sa += __shfl_xor(sa, off, 64);
            sb += __shfl_xor(sb, off, 64);
            sc += __shfl_xor(sc, off, 64);
        }
        const float mu   = sa * (1.0f / CDIM);
        const float dens = (sc - mu * sumS) * rsqrtf(sb - sa * mu);
        if (dens > best) { best = dens; bestn = nbase + r; }
    }
    if (lane == 0) wbest[wave] = pack_key(best, bestn);
    __syncthreads();
    if (t == 0) {
        unsigned long long m = wbest[0];
#pragma unroll
        for (int w = 1; w < 4; ++w) m = m > wbest[w] ? m : wbest[w];
        bests[blk] = m;
    }
}

// ---- k4: argmax over 128 bests; LN(argmax row) -> proj -> relu (8 blocks) ----
__global__ __launch_bounds__(256) void k4(const float* __restrict__ x,
                                          const float* __restrict__ lnw,
                                          const float* __restrict__ lnb,
                                          const float* __restrict__ pw,
                                          const float* __restrict__ pb,
                                          const unsigned long long* __restrict__ bests,
                                          float* __restrict__ out) {
    const int bb = blockIdx.x, t = threadIdx.x, wave = t >> 6, lane = t & 63;
    __shared__ unsigned long long wbest[4];
    __shared__ float sred[8];
    __shared__ float y[CDIM];

    unsigned long long v64 = (t < BPB) ? bests[(size_t)bb * BPB + t] : 0ULL;
#pragma unroll
    for (int off = 1; off < 64; off <<= 1) {
        const unsigned long long o = __shfl_xor(v64, off, 64);
        v64 = o > v64 ? o : v64;
    }
    if (lane == 0) wbest[wave] = v64;
    __syncthreads();
    unsigned long long m = wbest[0];
#pragma unroll
    for (int w = 1; w < 4; ++w) m = m > wbest[w] ? m : wbest[w];
    const int n = (int)(m & 0xFFFFFFFFULL);

    const float* row = x + ((size_t)bb * NROW + n) * CDIM;
    const float v = row[t];

    float s = v;
#pragma unroll
    for (int off = 1; off < 64; off <<= 1) s += __shfl_xor(s, off, 64);
    if (lane == 0) sred[wave] = s;
    __syncthreads();
    const float mu = (sred[0] + sred[1] + sred[2] + sred[3]) * (1.0f / CDIM);

    const float d = v - mu;
    float s2 = d * d;
#pragma unroll
    for (int off = 1; off < 64; off <<= 1) s2 += __shfl_xor(s2, off, 64);
    if (lane == 0) sred[4 + wave] = s2;
    __syncthreads();
    const float var = (sred[4] + sred[5] + sred[6] + sred[7]) * (1.0f / CDIM);
    const float rs  = rsqrtf(var + 1e-5f);

    y[t] = d * rs * lnw[t] + lnb[t];
    __syncthreads();

    const int dcol = t >> 2;
    const int part = t & 3;
    const float* wrow = pw + dcol * CDIM + part * 64;
    const float* yp   = y + part * 64;
    float p = 0.f;
#pragma unroll
    for (int c = 0; c < 64; ++c) p += yp[c] * wrow[c];
    p += __shfl_xor(p, 1, 64);
    p += __shfl_xor(p, 2, 64);
    if (part == 0) out[bb * CR + dcol] = fmaxf(p + pb[dcol], 0.0f);
}

// ------------------------------------------------------------------ launch ----
extern "C" void kernel_launch(void* const* d_in, const int* in_sizes, int n_in,
                              void* d_out, int out_size, void* d_ws, size_t ws_size,
                              hipStream_t stream) {
    const float* x   = (const float*)d_in[0];
    const float* lnw = (const float*)d_in[1];
    const float* lnb = (const float*)d_in[2];
    const float* pw  = (const float*)d_in[3];
    const float* pb  = (const float*)d_in[4];
    float* out = (float*)d_out;

    float* S_part = (float*)d_ws;
    float* S_mid  = (float*)((char*)d_ws + OFF_MID);
    unsigned long long* bests = (unsigned long long*)((char*)d_ws + OFF_BESTS);

    k1<<<GRID,          256, 0, stream>>>(x, S_part);
    ks<<<NBATCH * NMID, 256, 0, stream>>>(S_part, S_mid);
    k3<<<GRID,          256, 0, stream>>>(x, S_mid, bests);
    k4<<<NBATCH,        256, 0, stream>>>(x, lnw, lnb, pw, pb, bests, out);
}

// Round 8
// 26.956 us; speedup vs baseline: 11.6664x; 1.0718x over previous
//
#include <hip/hip_runtime.h>
#include <cstdint>
#include <cstddef>

constexpr int CDIM   = 256;   // channels
constexpr int CR     = 64;    // reduced channels
constexpr int NROW   = 4096;  // tokens per batch
constexpr int NBATCH = 8;

// k1: 256 blocks x 1024 threads
constexpr int K1_GRID = 256;
constexpr int K1_BPB  = K1_GRID / NBATCH;   // 32 blocks per batch
constexpr int K1_RPB  = NROW / K1_BPB;      // 128 rows per block
constexpr int K1_RPW  = K1_RPB / 16;        // 8 rows per wave (16 waves)

// k3: 1024 blocks x 256 threads
constexpr int K3_GRID = 1024;
constexpr int K3_BPB  = K3_GRID / NBATCH;   // 128 blocks per batch
constexpr int K3_RPB  = NROW / K3_BPB;      // 32 rows per block
constexpr int K3_RPW  = K3_RPB / 4;         // 8 rows per wave (4 waves)

// ws: S_part [256*256] f32 (256 KB) | rowstat [8*4096] float2 (256 KB) | bests [1024] u64
constexpr size_t OFF_STAT  = (size_t)K1_GRID * CDIM * sizeof(float);
constexpr size_t OFF_BESTS = OFF_STAT + (size_t)NBATCH * NROW * sizeof(float2);

__device__ __forceinline__ unsigned long long pack_key(float best, int n) {
    unsigned key = __float_as_uint(best);
    key = (key & 0x80000000u) ? ~key : (key | 0x80000000u);   // order-preserving
    return ((unsigned long long)key << 32) | (unsigned)n;
}

// ---- k1: per-block partial S (32/batch) + per-row {mu, inv} stats ----
__global__ __launch_bounds__(1024) void k1(const float* __restrict__ x,
                                           float* __restrict__ S_part,
                                           float2* __restrict__ rowstat) {
    const int blk = blockIdx.x, t = threadIdx.x, wave = t >> 6, lane = t & 63;
    __shared__ float comb[16][CDIM];            // 16 KB

    const int b = blk / K1_BPB, chunk = blk % K1_BPB;
    const float* xb = x + (size_t)b * NROW * CDIM;
    const int nbase = chunk * K1_RPB + wave * K1_RPW;

    float a0 = 0.f, a1 = 0.f, a2 = 0.f, a3 = 0.f;
#pragma unroll
    for (int r = 0; r < K1_RPW; ++r) {
        const int n = nbase + r;
        const float4 v = *reinterpret_cast<const float4*>(
            xb + (size_t)n * CDIM + lane * 4);
        float sa = v.x + v.y + v.z + v.w;
        float sb = v.x * v.x + v.y * v.y + v.z * v.z + v.w * v.w;
#pragma unroll
        for (int off = 1; off < 64; off <<= 1) {
            sa += __shfl_xor(sa, off, 64);
            sb += __shfl_xor(sb, off, 64);
        }
        const float mu  = sa * (1.0f / CDIM);
        const float inv = rsqrtf(sb - sa * mu);   // ln-eps & rsqrt scale cancel in u
        if (lane == 0) rowstat[(size_t)b * NROW + n] = make_float2(mu, inv);
        a0 += (v.x - mu) * inv;
        a1 += (v.y - mu) * inv;
        a2 += (v.z - mu) * inv;
        a3 += (v.w - mu) * inv;
    }
    *reinterpret_cast<float4*>(&comb[wave][lane * 4]) = make_float4(a0, a1, a2, a3);
    __syncthreads();
    if (t < CDIM) {
        float s = 0.f;
#pragma unroll
        for (int w = 0; w < 16; ++w) s += comb[w][t];
        S_part[(size_t)blk * CDIM + t] = s;
    }
}

// ---- k3: S from 32 partials; density via cached stats; per-block best ----
__global__ __launch_bounds__(256) void k3(const float* __restrict__ x,
                                          const float* __restrict__ S_part,
                                          const float2* __restrict__ rowstat,
                                          unsigned long long* __restrict__ bests) {
    const int blk = blockIdx.x, t = threadIdx.x, wave = t >> 6, lane = t & 63;
    const int b = blk / K3_BPB, chunk = blk % K3_BPB;

    __shared__ float comb[CDIM];
    __shared__ unsigned long long wbest[4];

    {   // sum this batch's 32 partials (coalesced, L2-hot)
        const float* Sp = S_part + (size_t)b * K1_BPB * CDIM;
        float s0 = 0.f, s1 = 0.f, s2 = 0.f, s3 = 0.f;
#pragma unroll
        for (int p = 0; p < K1_BPB; p += 4) {
            s0 += Sp[(size_t)(p + 0) * CDIM + t];
            s1 += Sp[(size_t)(p + 1) * CDIM + t];
            s2 += Sp[(size_t)(p + 2) * CDIM + t];
            s3 += Sp[(size_t)(p + 3) * CDIM + t];
        }
        comb[t] = (s0 + s1) + (s2 + s3);
    }
    __syncthreads();
    const float4 Sv = *reinterpret_cast<const float4*>(&comb[lane * 4]);
    float sumS = Sv.x + Sv.y + Sv.z + Sv.w;
#pragma unroll
    for (int off = 1; off < 64; off <<= 1) sumS += __shfl_xor(sumS, off, 64);

    const float* xb = x + (size_t)b * NROW * CDIM;
    const float2* stb = rowstat + (size_t)b * NROW;
    const int nbase = chunk * K3_RPB + wave * K3_RPW;
    float best = -1e30f;
    int   bestn = 0;
#pragma unroll
    for (int r = 0; r < K3_RPW; ++r) {
        const int n = nbase + r;
        const float4 v = *reinterpret_cast<const float4*>(
            xb + (size_t)n * CDIM + lane * 4);
        const float2 st = stb[n];                 // broadcast load
        float sc = v.x * Sv.x + v.y * Sv.y + v.z * Sv.z + v.w * Sv.w;
#pragma unroll
        for (int off = 1; off < 64; off <<= 1) sc += __shfl_xor(sc, off, 64);
        const float dens = (sc - st.x * sumS) * st.y;
        if (dens > best) { best = dens; bestn = n; }
    }
    if (lane == 0) wbest[wave] = pack_key(best, bestn);
    __syncthreads();
    if (t == 0) {
        unsigned long long m = wbest[0];
#pragma unroll
        for (int w = 1; w < 4; ++w) m = m > wbest[w] ? m : wbest[w];
        bests[blk] = m;
    }
}

// ---- k4: argmax over 128 bests; LN(argmax row) -> proj -> relu (8 blocks) ----
__global__ __launch_bounds__(256) void k4(const float* __restrict__ x,
                                          const float* __restrict__ lnw,
                                          const float* __restrict__ lnb,
                                          const float* __restrict__ pw,
                                          const float* __restrict__ pb,
                                          const unsigned long long* __restrict__ bests,
                                          float* __restrict__ out) {
    const int bb = blockIdx.x, t = threadIdx.x, wave = t >> 6, lane = t & 63;
    __shared__ unsigned long long wbest[4];
    __shared__ float sred[8];
    __shared__ float y[CDIM];

    unsigned long long v64 = (t < K3_BPB) ? bests[(size_t)bb * K3_BPB + t] : 0ULL;
#pragma unroll
    for (int off = 1; off < 64; off <<= 1) {
        const unsigned long long o = __shfl_xor(v64, off, 64);
        v64 = o > v64 ? o : v64;
    }
    if (lane == 0) wbest[wave] = v64;
    __syncthreads();
    unsigned long long m = wbest[0];
#pragma unroll
    for (int w = 1; w < 4; ++w) m = m > wbest[w] ? m : wbest[w];
    const int n = (int)(m & 0xFFFFFFFFULL);

    const float* row = x + ((size_t)bb * NROW + n) * CDIM;
    const float v = row[t];

    float s = v;
#pragma unroll
    for (int off = 1; off < 64; off <<= 1) s += __shfl_xor(s, off, 64);
    if (lane == 0) sred[wave] = s;
    __syncthreads();
    const float mu = (sred[0] + sred[1] + sred[2] + sred[3]) * (1.0f / CDIM);

    const float d = v - mu;
    float s2 = d * d;
#pragma unroll
    for (int off = 1; off < 64; off <<= 1) s2 += __shfl_xor(s2, off, 64);
    if (lane == 0) sred[4 + wave] = s2;
    __syncthreads();
    const float var = (sred[4] + sred[5] + sred[6] + sred[7]) * (1.0f / CDIM);
    const float rs  = rsqrtf(var + 1e-5f);

    y[t] = d * rs * lnw[t] + lnb[t];
    __syncthreads();

    const int dcol = t >> 2;
    const int part = t & 3;
    const float* wrow = pw + dcol * CDIM + part * 64;
    const float* yp   = y + part * 64;
    float p = 0.f;
#pragma unroll
    for (int c = 0; c < 64; ++c) p += yp[c] * wrow[c];
    p += __shfl_xor(p, 1, 64);
    p += __shfl_xor(p, 2, 64);
    if (part == 0) out[bb * CR + dcol] = fmaxf(p + pb[dcol], 0.0f);
}

// ------------------------------------------------------------------ launch ----
extern "C" void kernel_launch(void* const* d_in, const int* in_sizes, int n_in,
                              void* d_out, int out_size, void* d_ws, size_t ws_size,
                              hipStream_t stream) {
    const float* x   = (const float*)d_in[0];
    const float* lnw = (const float*)d_in[1];
    const float* lnb = (const float*)d_in[2];
    const float* pw  = (const float*)d_in[3];
    const float* pb  = (const float*)d_in[4];
    float* out = (float*)d_out;

    float* S_part   = (float*)d_ws;
    float2* rowstat = (float2*)((char*)d_ws + OFF_STAT);
    unsigned long long* bests = (unsigned long long*)((char*)d_ws + OFF_BESTS);

    k1<<<K1_GRID, 1024, 0, stream>>>(x, S_part, rowstat);
    k3<<<K3_GRID, 256,  0, stream>>>(x, S_part, rowstat, bests);
    k4<<<NBATCH,  256,  0, stream>>>(x, lnw, lnb, pw, pb, bests, out);
}

// Round 9
// 26.168 us; speedup vs baseline: 12.0176x; 1.0301x over previous
//
#include <hip/hip_runtime.h>
#include <cstdint>
#include <cstddef>

constexpr int CDIM   = 256;   // channels
constexpr int CR     = 64;    // reduced channels
constexpr int NROW   = 4096;  // tokens per batch
constexpr int NBATCH = 8;

// k1: 256 blocks x 1024 threads (16 waves), 128 rows/block
constexpr int K1_GRID = 256;
constexpr int K1_BPB  = K1_GRID / NBATCH;   // 32 blocks per batch
constexpr int K1_RPB  = NROW / K1_BPB;      // 128 rows per block
// per wave: 128/16 = 8 rows = 2 groups of 4

// k2: 1024 blocks x 256 threads, 32 rows/block, 8 rows/wave = 2 groups
constexpr int K2_GRID = 1024;
constexpr int K2_BPB  = K2_GRID / NBATCH;   // 128 blocks per batch
constexpr int K2_RPB  = NROW / K2_BPB;      // 32 rows per block

// ws: S_part [256*256] f32 (256 KB) | S_fin [8*256] f32 (8 KB) | bests [1024] u64
constexpr size_t OFF_SFIN  = (size_t)K1_GRID * CDIM * sizeof(float);
constexpr size_t OFF_BESTS = OFF_SFIN + (size_t)NBATCH * CDIM * sizeof(float);

__device__ __forceinline__ unsigned long long pack_key(float best, int n) {
    unsigned key = __float_as_uint(best);
    key = (key & 0x80000000u) ? ~key : (key | 0x80000000u);   // order-preserving
    return ((unsigned long long)key << 32) | (unsigned)n;
}

// ---- k1: partial S per block (32/batch). 16-lane row groups, 4 rows/wave-iter ----
__global__ __launch_bounds__(1024) void k1(const float* __restrict__ x,
                                           float* __restrict__ S_part) {
    const int blk = blockIdx.x, t = threadIdx.x;
    const int wave = t >> 6, lane = t & 63;
    const int g = lane >> 4, sub = lane & 15;
    __shared__ float comb[16][CDIM];            // 16 KB

    const int b = blk / K1_BPB, chunk = blk % K1_BPB;
    const float* xb = x + (size_t)b * NROW * CDIM;
    const int nbase = chunk * K1_RPB + wave * 8;   // 8 rows per wave

    float4 a0 = {0,0,0,0}, a1 = {0,0,0,0}, a2 = {0,0,0,0}, a3 = {0,0,0,0};
#pragma unroll
    for (int rg = 0; rg < 2; ++rg) {
        const int n = nbase + rg * 4 + g;
        const float* rowp = xb + (size_t)n * CDIM + sub * 4;
        const float4 v0 = *reinterpret_cast<const float4*>(rowp);
        const float4 v1 = *reinterpret_cast<const float4*>(rowp + 64);
        const float4 v2 = *reinterpret_cast<const float4*>(rowp + 128);
        const float4 v3 = *reinterpret_cast<const float4*>(rowp + 192);

        float sa = (v0.x+v0.y+v0.z+v0.w) + (v1.x+v1.y+v1.z+v1.w)
                 + (v2.x+v2.y+v2.z+v2.w) + (v3.x+v3.y+v3.z+v3.w);
        float sb = (v0.x*v0.x+v0.y*v0.y+v0.z*v0.z+v0.w*v0.w)
                 + (v1.x*v1.x+v1.y*v1.y+v1.z*v1.z+v1.w*v1.w)
                 + (v2.x*v2.x+v2.y*v2.y+v2.z*v2.z+v2.w*v2.w)
                 + (v3.x*v3.x+v3.y*v3.y+v3.z*v3.z+v3.w*v3.w);
#pragma unroll
        for (int off = 1; off < 16; off <<= 1) {   // 16-lane group reduce, 4 rows at once
            sa += __shfl_xor(sa, off, 64);
            sb += __shfl_xor(sb, off, 64);
        }
        const float mu  = sa * (1.0f / CDIM);
        const float inv = rsqrtf(sb - sa * mu);    // ln-eps & rsqrt scale cancel in u
        a0.x += (v0.x-mu)*inv; a0.y += (v0.y-mu)*inv; a0.z += (v0.z-mu)*inv; a0.w += (v0.w-mu)*inv;
        a1.x += (v1.x-mu)*inv; a1.y += (v1.y-mu)*inv; a1.z += (v1.z-mu)*inv; a1.w += (v1.w-mu)*inv;
        a2.x += (v2.x-mu)*inv; a2.y += (v2.y-mu)*inv; a2.z += (v2.z-mu)*inv; a2.w += (v2.w-mu)*inv;
        a3.x += (v3.x-mu)*inv; a3.y += (v3.y-mu)*inv; a3.z += (v3.z-mu)*inv; a3.w += (v3.w-mu)*inv;
    }
    // pre-reduce the 4 groups (same columns, different rows): xor 16, 32
#pragma unroll
    for (int off = 16; off < 64; off <<= 1) {
        a0.x += __shfl_xor(a0.x, off, 64); a0.y += __shfl_xor(a0.y, off, 64);
        a0.z += __shfl_xor(a0.z, off, 64); a0.w += __shfl_xor(a0.w, off, 64);
        a1.x += __shfl_xor(a1.x, off, 64); a1.y += __shfl_xor(a1.y, off, 64);
        a1.z += __shfl_xor(a1.z, off, 64); a1.w += __shfl_xor(a1.w, off, 64);
        a2.x += __shfl_xor(a2.x, off, 64); a2.y += __shfl_xor(a2.y, off, 64);
        a2.z += __shfl_xor(a2.z, off, 64); a2.w += __shfl_xor(a2.w, off, 64);
        a3.x += __shfl_xor(a3.x, off, 64); a3.y += __shfl_xor(a3.y, off, 64);
        a3.z += __shfl_xor(a3.z, off, 64); a3.w += __shfl_xor(a3.w, off, 64);
    }
    if (g == 0) {   // lanes 0..15 hold the wave's column sums
        *reinterpret_cast<float4*>(&comb[wave][sub * 4 +   0]) = a0;
        *reinterpret_cast<float4*>(&comb[wave][sub * 4 +  64]) = a1;
        *reinterpret_cast<float4*>(&comb[wave][sub * 4 + 128]) = a2;
        *reinterpret_cast<float4*>(&comb[wave][sub * 4 + 192]) = a3;
    }
    __syncthreads();
    if (t < CDIM) {
        float s = 0.f;
#pragma unroll
        for (int w = 0; w < 16; ++w) s += comb[w][t];
        S_part[(size_t)blk * CDIM + t] = s;
    }
}

// ---- ks: final S per batch (8 blocks): sum 32 partials, float4-split ----
__global__ __launch_bounds__(256) void ks(const float* __restrict__ S_part,
                                          float* __restrict__ S_fin) {
    const int b = blockIdx.x, t = threadIdx.x;
    const int c4 = t & 63, pg = t >> 2 >> 4;   // pg = t>>6 (0..3)
    __shared__ float4 acc[4][64];
    const float4* Sp = reinterpret_cast<const float4*>(
        S_part + (size_t)(b * K1_BPB + pg * 8) * CDIM);
    float4 s = {0,0,0,0};
#pragma unroll
    for (int p = 0; p < 8; ++p) {
        const float4 v = Sp[(size_t)p * 64 + c4];
        s.x += v.x; s.y += v.y; s.z += v.z; s.w += v.w;
    }
    acc[pg][c4] = s;
    __syncthreads();
    if (t < 64) {
        const float4 q0 = acc[0][t], q1 = acc[1][t], q2 = acc[2][t], q3 = acc[3][t];
        float4 r;
        r.x = (q0.x + q1.x) + (q2.x + q3.x);
        r.y = (q0.y + q1.y) + (q2.y + q3.y);
        r.z = (q0.z + q1.z) + (q2.z + q3.z);
        r.w = (q0.w + q1.w) + (q2.w + q3.w);
        reinterpret_cast<float4*>(S_fin)[(size_t)b * 64 + t] = r;
    }
}

// ---- k2: density via 16-lane groups (3-value reduce); per-block best ----
__global__ __launch_bounds__(256) void k2(const float* __restrict__ x,
                                          const float* __restrict__ S_fin,
                                          unsigned long long* __restrict__ bests) {
    const int blk = blockIdx.x, t = threadIdx.x;
    const int wave = t >> 6, lane = t & 63;
    const int g = lane >> 4, sub = lane & 15;
    const int b = blk / K2_BPB, chunk = blk % K2_BPB;

    __shared__ float comb[CDIM];
    __shared__ unsigned long long wbest[4];

    comb[t] = S_fin[(size_t)b * CDIM + t];       // 1 KB coalesced, L2-hot
    __syncthreads();

    float4 S0 = *reinterpret_cast<const float4*>(&comb[sub * 4 +   0]);
    float4 S1 = *reinterpret_cast<const float4*>(&comb[sub * 4 +  64]);
    float4 S2 = *reinterpret_cast<const float4*>(&comb[sub * 4 + 128]);
    float4 S3 = *reinterpret_cast<const float4*>(&comb[sub * 4 + 192]);

    float sumS = (S0.x+S0.y+S0.z+S0.w) + (S1.x+S1.y+S1.z+S1.w)
               + (S2.x+S2.y+S2.z+S2.w) + (S3.x+S3.y+S3.z+S3.w);
#pragma unroll
    for (int off = 1; off < 16; off <<= 1) sumS += __shfl_xor(sumS, off, 64);

    const float* xb = x + (size_t)b * NROW * CDIM;
    const int nbase = chunk * K2_RPB + wave * 8;
    float best = -1e30f;
    int   bestn = 0;
#pragma unroll
    for (int rg = 0; rg < 2; ++rg) {
        const int n = nbase + rg * 4 + g;
        const float* rowp = xb + (size_t)n * CDIM + sub * 4;
        const float4 v0 = *reinterpret_cast<const float4*>(rowp);
        const float4 v1 = *reinterpret_cast<const float4*>(rowp + 64);
        const float4 v2 = *reinterpret_cast<const float4*>(rowp + 128);
        const float4 v3 = *reinterpret_cast<const float4*>(rowp + 192);

        float sa = (v0.x+v0.y+v0.z+v0.w) + (v1.x+v1.y+v1.z+v1.w)
                 + (v2.x+v2.y+v2.z+v2.w) + (v3.x+v3.y+v3.z+v3.w);
        float sb = (v0.x*v0.x+v0.y*v0.y+v0.z*v0.z+v0.w*v0.w)
                 + (v1.x*v1.x+v1.y*v1.y+v1.z*v1.z+v1.w*v1.w)
                 + (v2.x*v2.x+v2.y*v2.y+v2.z*v2.z+v2.w*v2.w)
                 + (v3.x*v3.x+v3.y*v3.y+v3.z*v3.z+v3.w*v3.w);
        float sc = (v0.x*S0.x+v0.y*S0.y+v0.z*S0.z+v0.w*S0.w)
                 + (v1.x*S1.x+v1.y*S1.y+v1.z*S1.z+v1.w*S1.w)
                 + (v2.x*S2.x+v2.y*S2.y+v2.z*S2.z+v2.w*S2.w)
                 + (v3.x*S3.x+v3.y*S3.y+v3.z*S3.z+v3.w*S3.w);
#pragma unroll
        for (int off = 1; off < 16; off <<= 1) {   // one butterfly, 4 rows at once
            sa += __shfl_xor(sa, off, 64);
            sb += __shfl_xor(sb, off, 64);
            sc += __shfl_xor(sc, off, 64);
        }
        const float mu   = sa * (1.0f / CDIM);
        const float dens = (sc - mu * sumS) * rsqrtf(sb - sa * mu);
        if (dens > best) { best = dens; bestn = n; }
    }
    unsigned long long key = pack_key(best, bestn);
    {   // reduce across the 4 groups
        unsigned long long o = __shfl_xor(key, 16, 64); key = o > key ? o : key;
        o = __shfl_xor(key, 32, 64);                    key = o > key ? o : key;
    }
    if (lane == 0) wbest[wave] = key;
    __syncthreads();
    if (t == 0) {
        unsigned long long m = wbest[0];
#pragma unroll
        for (int w = 1; w < 4; ++w) m = m > wbest[w] ? m : wbest[w];
        bests[blk] = m;
    }
}

// ---- k4: argmax over 128 bests; LN(argmax row) -> proj -> relu (8 blocks) ----
__global__ __launch_bounds__(256) void k4(const float* __restrict__ x,
                                          const float* __restrict__ lnw,
                                          const float* __restrict__ lnb,
                                          const float* __restrict__ pw,
                                          const float* __restrict__ pb,
                                          const unsigned long long* __restrict__ bests,
                                          float* __restrict__ out) {
    const int bb = blockIdx.x, t = threadIdx.x, wave = t >> 6, lane = t & 63;
    __shared__ unsigned long long wbest[4];
    __shared__ float sred[8];
    __shared__ float y[CDIM];

    unsigned long long v64 = (t < K2_BPB) ? bests[(size_t)bb * K2_BPB + t] : 0ULL;
#pragma unroll
    for (int off = 1; off < 64; off <<= 1) {
        const unsigned long long o = __shfl_xor(v64, off, 64);
        v64 = o > v64 ? o : v64;
    }
    if (lane == 0) wbest[wave] = v64;
    __syncthreads();
    unsigned long long m = wbest[0];
#pragma unroll
    for (int w = 1; w < 4; ++w) m = m > wbest[w] ? m : wbest[w];
    const int n = (int)(m & 0xFFFFFFFFULL);

    const float* row = x + ((size_t)bb * NROW + n) * CDIM;
    const float v = row[t];

    float s = v;
#pragma unroll
    for (int off = 1; off < 64; off <<= 1) s += __shfl_xor(s, off, 64);
    if (lane == 0) sred[wave] = s;
    __syncthreads();
    const float mu = (sred[0] + sred[1] + sred[2] + sred[3]) * (1.0f / CDIM);

    const float d = v - mu;
    float s2 = d * d;
#pragma unroll
    for (int off = 1; off < 64; off <<= 1) s2 += __shfl_xor(s2, off, 64);
    if (lane == 0) sred[4 + wave] = s2;
    __syncthreads();
    const float var = (sred[4] + sred[5] + sred[6] + sred[7]) * (1.0f / CDIM);
    const float rs  = rsqrtf(var + 1e-5f);

    y[t] = d * rs * lnw[t] + lnb[t];
    __syncthreads();

    const int dcol = t >> 2;
    const int part = t & 3;
    const float* wrow = pw + dcol * CDIM + part * 64;
    const float* yp   = y + part * 64;
    float p = 0.f;
#pragma unroll
    for (int c = 0; c < 64; ++c) p += yp[c] * wrow[c];
    p += __shfl_xor(p, 1, 64);
    p += __shfl_xor(p, 2, 64);
    if (part == 0) out[bb * CR + dcol] = fmaxf(p + pb[dcol], 0.0f);
}

// ------------------------------------------------------------------ launch ----
extern "C" void kernel_launch(void* const* d_in, const int* in_sizes, int n_in,
                              void* d_out, int out_size, void* d_ws, size_t ws_size,
                              hipStream_t stream) {
    const float* x   = (const float*)d_in[0];
    const float* lnw = (const float*)d_in[1];
    const float* lnb = (const float*)d_in[2];
    const float* pw  = (const float*)d_in[3];
    const float* pb  = (const float*)d_in[4];
    float* out = (float*)d_out;

    float* S_part = (float*)d_ws;
    float* S_fin  = (float*)((char*)d_ws + OFF_SFIN);
    unsigned long long* bests = (unsigned long long*)((char*)d_ws + OFF_BESTS);

    k1<<<K1_GRID, 1024, 0, stream>>>(x, S_part);
    ks<<<NBATCH,  256,  0, stream>>>(S_part, S_fin);
    k2<<<K2_GRID, 256,  0, stream>>>(x, S_fin, bests);
    k4<<<NBATCH,  256,  0, stream>>>(x, lnw, lnb, pw, pb, bests, out);
}